// Round 6
// baseline (2797.206 us; speedup 1.0000x reference)
//
#include <hip/hip_runtime.h>

typedef __bf16 bf16x8 __attribute__((ext_vector_type(8)));
typedef float  f32x4  __attribute__((ext_vector_type(4)));

union U4 { uint4 u; bf16x8 v; };

__device__ __forceinline__ bf16x8 ld_frag(const void* p) {
    U4 t; t.u = *(const uint4*)p; return t.v;
}
__device__ __forceinline__ bf16x8 zfrag() {
    bf16x8 z;
#pragma unroll
    for (int jj = 0; jj < 8; jj++) z[jj] = (__bf16)0.f;
    return z;
}
// agent-scope (device) 16B load as 2x8B relaxed atomics: bypasses stale caches,
// placement-independent correctness for cross-block h traffic.
__device__ __forceinline__ bf16x8 ald_frag(const void* p) {
    union { unsigned long long q[2]; bf16x8 v; } t;
    unsigned long long* u = (unsigned long long*)p;
    t.q[0] = __hip_atomic_load(u,     __ATOMIC_RELAXED, __HIP_MEMORY_SCOPE_AGENT);
    t.q[1] = __hip_atomic_load(u + 1, __ATOMIC_RELAXED, __HIP_MEMORY_SCOPE_AGENT);
    return t.v;
}
__device__ __forceinline__ float ald_bf16(const void* p) {
    unsigned short s = __hip_atomic_load((unsigned short*)p, __ATOMIC_RELAXED,
                                         __HIP_MEMORY_SCOPE_AGENT);
    unsigned u = ((unsigned)s) << 16; float f;
    __builtin_memcpy(&f, &u, 4); return f;
}
__device__ __forceinline__ void ast_bf16(void* p, float f) {
    __bf16 h = (__bf16)f; unsigned short s;
    __builtin_memcpy(&s, &h, 2);
    __hip_atomic_store((unsigned short*)p, s, __ATOMIC_RELAXED,
                       __HIP_MEMORY_SCOPE_AGENT);
}

__device__ __forceinline__ void gl_lds16(const uint4* g, void* l) {
    __builtin_amdgcn_global_load_lds(
        (const __attribute__((address_space(1))) unsigned int*)g,
        (__attribute__((address_space(3))) unsigned int*)l, 16, 0, 0);
}

__device__ __forceinline__ float sigf(float x) {
    return __builtin_amdgcn_rcpf(1.f + __expf(-x));
}
__device__ __forceinline__ float tanhf_fast(float x) {
    return 1.f - 2.f * __builtin_amdgcn_rcpf(1.f + __expf(2.f * x));
}

#define MFMA(A,B,C) C = __builtin_amdgcn_mfma_f32_16x16x32_bf16(A, B, C, 0, 0, 0)

// ---------------------------------------------------------------------------
// pack: [Wx(16,pad 32); Uh(256); Uh2(256)] -> B-fragments
// pack[a][kt17][nt48][lane64] = 8 bf16 : B[kt*32+(lane>>4)*8+jj][nt*16+(lane&15)]
// ---------------------------------------------------------------------------
__global__ void pack_kernel(const float* __restrict__ Wx, const float* __restrict__ Uh,
                            const float* __restrict__ Uh2, uint4* __restrict__ packW) {
    int tid = blockIdx.x * 256 + threadIdx.x;   // 4*17*48*64 = 208896
    int lane = tid & 63;
    int nt   = (tid >> 6) % 48;
    int kt   = ((tid >> 6) / 48) % 17;
    int a    = (tid >> 6) / (48 * 17);
    int col  = nt * 16 + (lane & 15);
    int kbase = kt * 32 + (lane >> 4) * 8;
    U4 u;
#pragma unroll
    for (int jj = 0; jj < 8; jj++) {
        int k = kbase + jj;
        float v;
        if (k < 16)       v = Wx[(a * 16 + k) * 768 + col];
        else if (k < 32)  v = 0.f;
        else if (k < 288) v = Uh[(a * 256 + (k - 32)) * 768 + col];
        else              v = Uh2[(a * 256 + (k - 288)) * 768 + col];
        u.v[jj] = (__bf16)v;
    }
    packW[tid] = u.u;
}

// xpack[a][i29][j29][m256][q2] = 8 bf16 of patch element k=q*8+jj
__global__ void xpack_kernel(const float* __restrict__ x, uint4* __restrict__ xp) {
    int tid = blockIdx.x * 256 + threadIdx.x;   // 1,722,368
    int q = tid & 1;
    int m = (tid >> 1) & 255;
    int rem = tid >> 9;
    int j = rem % 29;
    int t2 = rem / 29;
    int i = t2 % 29;
    int a = t2 / 29;
    int Ny = 29 - (a & 1), Nx = 29 - ((a >> 1) & 1);
    U4 u;
    if (i < Ny && j < Nx) {
        int y0 = (a & 1) ? (27 - i) : i;
        int x0 = (a & 2) ? (27 - j) : j;
        const float* px = x + m * 1024 + y0 * 32 + x0;
#pragma unroll
        for (int jj = 0; jj < 8; jj++) {
            int k = q * 8 + jj;
            u.v[jj] = (__bf16)px[(k >> 2) * 32 + (k & 3)];
        }
    } else {
#pragma unroll
        for (int jj = 0; jj < 8; jj++) u.v[jj] = (__bf16)0.f;
    }
    xp[tid] = u.u;
}

// ---------------------------------------------------------------------------
// Persistent kernel. 256 blocks x 512 thr (cooperative). Block = (G, r):
//   G = bx&7 : group (a = G>>1 direction, hb = G&1 batch-half, M=128)
//   r = bx>>3: g = r&7 (32 hidden cols), qi0 = r>>3 (quad lane 0..3)
// Groups are fully independent scans; per-group 32-block atomic barrier per
// diagonal. B for (a,g) loaded ONCE into 102 KB LDS. Wave-pair wp=tid>>7
// handles one cell of the quad; wave wv=(tid>>6)&1 covers M64 (mt=4) x N96.
// hbuf per group: [p2][j29][kt8][m128][c32] bf16 (slice 65536 B).
// acc[mt][cf]: cf = gate*2+half; gates r,z,n(h-part); x-stage fused at end.
// ---------------------------------------------------------------------------
__global__ __launch_bounds__(512, 2) void persist_kernel(
    const float* __restrict__ x, const uint4* __restrict__ xpack,
    const uint4* __restrict__ packW, const float* __restrict__ bias,
    char* __restrict__ hbuf, unsigned* __restrict__ cnts)
{
    extern __shared__ __align__(16) unsigned char smem[];   // 104448 B

    int bx = blockIdx.x;
    int G  = bx & 7;
    int r  = bx >> 3;
    int a  = G >> 1, hb = G & 1;
    int g  = r & 7, qi0 = r >> 3;
    int Ny = 29 - (a & 1), Nx = 29 - ((a >> 1) & 1);
    int Dg = Ny + Nx - 1;
    char* hbg = hbuf + (size_t)G * 3801088;
    unsigned* cnt = cnts + G * 32;   // 128 B spacing

    int tid  = threadIdx.x;
    int w8   = tid >> 6;          // wave 0..7
    int wp   = tid >> 7;          // wave-pair 0..3 (cell within quad)
    int wv   = (tid >> 6) & 1;    // M64 half within pair
    int lane = tid & 63;
    int q    = lane >> 4;
    int l16  = lane & 15;

    // ---- one-time B preload: 102 chunks x 1 KB ----
    for (int c = w8; c < 102; c += 8) {
        int s  = c / 6;
        int cc = c - s * 6;
        int kt = (s == 16) ? 0 : (s + 1);
        int nt = (cc >> 1) * 16 + 2 * g + (cc & 1);
        gl_lds16(packW + (size_t)(a * 17 + kt) * 3072 + nt * 64 + lane,
                 smem + (size_t)c * 1024);
    }
    __syncthreads();

    int rowoff = wv * 4096 + l16 * 64 + q * 16;
    const float* ba = bias + a * 768;

    for (int d = 0; d < Dg; ++d) {
        int lo = d - (Ny - 1); if (lo < 0) lo = 0;
        int hi = (d < Nx - 1) ? d : Nx - 1;
        int nquad = (hi - lo + 4) >> 2;
        int pprev = (d - 1) & 1;
        int pcur  = d & 1;

        for (int qi = qi0; qi < nquad; qi += 4) {
            int j = lo + qi * 4 + wp;
            if (j > hi) continue;                 // wave-pair-uniform
            int i = d - j;
            bool hasA = (i > 0);
            bool hasL = (j > 0);
            const char* sA = hbg + (size_t)(pprev * 29 + j) * 65536;
            const char* sL = hbg + (size_t)(pprev * 29 + (j - 1)) * 65536;

            f32x4 acc[4][6];
#pragma unroll
            for (int mt = 0; mt < 4; mt++)
#pragma unroll
                for (int cf = 0; cf < 6; cf++)
#pragma unroll
                    for (int e = 0; e < 4; e++) acc[mt][cf][e] = 0.f;

            bf16x8 af[4][4];
            auto issueA = [&](int s, bf16x8* dst) {
                if (s >= 16) return;
                bool act = (s < 8) ? hasA : hasL;
                if (!act) return;
                const char* sb = ((s < 8) ? sA : sL) + (size_t)(s & 7) * 8192 + rowoff;
#pragma unroll
                for (int mt = 0; mt < 4; mt++) dst[mt] = ald_frag(sb + mt * 1024);
            };
            auto compute = [&](const bf16x8* afc, int s) {
                const unsigned char* bb = smem + (size_t)s * 6144 + lane * 16;
#pragma unroll
                for (int cf = 0; cf < 6; cf++) {
                    bf16x8 bf = ld_frag(bb + cf * 1024);
#pragma unroll
                    for (int mt = 0; mt < 4; mt++) MFMA(afc[mt], bf, acc[mt][cf]);
                }
            };

            issueA(0, af[0]); issueA(1, af[1]); issueA(2, af[2]); issueA(3, af[3]);
#pragma unroll
            for (int s = 0; s < 16; ++s) {
                bool act = (s < 8) ? hasA : hasL;
                if (act) compute(af[s & 3], s);
                issueA(s + 4, af[s & 3]);
            }

            // ---- x-stage A fragments ----
            bf16x8 afx[4];
            if (xpack) {
                const uint4* xpc = xpack + (size_t)((a * 29 + i) * 29 + j) * 512
                                  + (size_t)(hb * 128) * 2 + q;
#pragma unroll
                for (int mt = 0; mt < 4; mt++) {
                    if (q < 2) afx[mt] = ld_frag(xpc + (wv * 64 + mt * 16 + l16) * 2);
                    else       afx[mt] = zfrag();
                }
            } else {
                int y0 = (a & 1) ? (27 - i) : i;
                int x0 = (a & 2) ? (27 - j) : j;
#pragma unroll
                for (int mt = 0; mt < 4; mt++) {
                    if (q < 2) {
                        int m = hb * 128 + wv * 64 + mt * 16 + l16;
                        const float* xp = x + m * 1024 + (y0 + 2 * q) * 32 + x0;
#pragma unroll
                        for (int jj = 0; jj < 8; jj++)
                            afx[mt][jj] = (__bf16)xp[(jj >> 2) * 32 + (jj & 3)];
                    } else afx[mt] = zfrag();
                }
            }
            // x contributions to r,z
            {
                const unsigned char* bb = smem + (size_t)16 * 6144 + lane * 16;
#pragma unroll
                for (int cf = 0; cf < 4; cf++) {
                    bf16x8 bf = ld_frag(bb + cf * 1024);
#pragma unroll
                    for (int mt = 0; mt < 4; mt++) MFMA(afx[mt], bf, acc[mt][cf]);
                }
            }
            // n-gate x-part per half, fused epilogue
            char* sO = hbg + (size_t)(pcur * 29 + j) * 65536;
#pragma unroll
            for (int half = 0; half < 2; half++) {
                bf16x8 bn = ld_frag(smem + (size_t)16 * 6144 + (4 + half) * 1024 + lane * 16);
                f32x4 tn[4];
#pragma unroll
                for (int mt = 0; mt < 4; mt++) {
                    f32x4 z4 = {0.f, 0.f, 0.f, 0.f};
                    tn[mt] = __builtin_amdgcn_mfma_f32_16x16x32_bf16(afx[mt], bn, z4, 0, 0, 0);
                }
                int c31 = half * 16 + l16;
                int c   = g * 32 + c31;
                float bR = ba[c], bZ = ba[256 + c], bN = ba[512 + c];
#pragma unroll
                for (int mt = 0; mt < 4; mt++) {
#pragma unroll
                    for (int e = 0; e < 4; e++) {
                        int m = wv * 64 + mt * 16 + q * 4 + e;
                        size_t off = (size_t)g * 8192 + (size_t)m * 64 + c31 * 2;
                        float rv = sigf(acc[mt][0 + half][e] + bR);
                        float zv = sigf(acc[mt][2 + half][e] + bZ);
                        float nv = tanhf_fast(tn[mt][e] + bN + rv * acc[mt][4 + half][e]);
                        float hs = 0.f;
                        if (hasA) hs += ald_bf16(sA + off);
                        if (hasL) hs += ald_bf16(sL + off);
                        ast_bf16(sO + off, (1.f - zv) * nv + 0.5f * zv * hs);
                    }
                }
            }
        }

        // ---- per-group barrier (32 blocks) ----
        __syncthreads();                       // drains vm stores of all waves
        if (tid == 0) {
            atomicAdd(cnt, 1u);
            unsigned need = 32u * (unsigned)(d + 1);
            while (__hip_atomic_load(cnt, __ATOMIC_RELAXED, __HIP_MEMORY_SCOPE_AGENT) < need)
                __builtin_amdgcn_s_sleep(2);
        }
        __syncthreads();
    }
}

// ---------------------------------------------------------------------------
// Output: logits = hcat @ W_out + b_out, then log_softmax. One wave per batch.
// h elem (a,c,b): G = a*2 + (b>>7); per-group slice layout as persist.
// ---------------------------------------------------------------------------
__global__ __launch_bounds__(64) void out_kernel(const char* __restrict__ hbuf,
    const float* __restrict__ Wout, const float* __restrict__ bout,
    float* __restrict__ out)
{
    int b = blockIdx.x;
    int tt = threadIdx.x;
    float accv[10];
#pragma unroll
    for (int o = 0; o < 10; o++) accv[o] = 0.f;
    for (int it = 0; it < 16; ++it) {
        int k = it * 64 + tt;
        int a = k >> 8, c = k & 255;
        int Ny = 29 - (a & 1), Nx = 29 - ((a >> 1) & 1);
        int pf = (Ny + Nx - 2) & 1;
        int jf = Nx - 1;
        int G  = a * 2 + (b >> 7);
        const __bf16* hp = (const __bf16*)(hbuf + (size_t)G * 3801088
                           + (size_t)(pf * 29 + jf) * 65536
                           + (size_t)(c >> 5) * 8192 + (size_t)(b & 127) * 64
                           + (size_t)(c & 31) * 2);
        float h = (float)(*hp);
        const float* wr = Wout + k * 10;
#pragma unroll
        for (int o = 0; o < 10; o++) accv[o] += h * wr[o];
    }
#pragma unroll
    for (int off = 32; off > 0; off >>= 1)
#pragma unroll
        for (int o = 0; o < 10; o++) accv[o] += __shfl_down(accv[o], off, 64);
    if (tt == 0) {
        float l[10];
#pragma unroll
        for (int o = 0; o < 10; o++) l[o] = accv[o] + bout[o];
        float mx = l[0];
#pragma unroll
        for (int o = 1; o < 10; o++) mx = fmaxf(mx, l[o]);
        float se = 0.f;
#pragma unroll
        for (int o = 0; o < 10; o++) se += __expf(l[o] - mx);
        float lse = mx + __logf(se);
#pragma unroll
        for (int o = 0; o < 10; o++) out[b * 10 + o] = l[o] - lse;
    }
}

extern "C" void kernel_launch(void* const* d_in, const int* in_sizes, int n_in,
                              void* d_out, int out_size, void* d_ws, size_t ws_size,
                              hipStream_t stream) {
    const float* x    = (const float*)d_in[0];
    const float* Wx   = (const float*)d_in[1];
    const float* Uh   = (const float*)d_in[2];
    const float* Uh2  = (const float*)d_in[3];
    const float* b    = (const float*)d_in[4];
    const float* Wout = (const float*)d_in[5];
    const float* bout = (const float*)d_in[6];
    float* out = (float*)d_out;

    char* ws = (char*)d_ws;
    const size_t XPACK_OFF    = 3407872;
    const size_t HBUF_OFF_BIG = 31457280;
    const size_t HBUF_BYTES   = 30408704;
    bool use_xp = (ws_size >= HBUF_OFF_BIG + HBUF_BYTES + 4096);

    uint4*  packW = (uint4*)ws;
    uint4*  xpack = use_xp ? (uint4*)(ws + XPACK_OFF) : nullptr;
    size_t  hbuf_off = use_xp ? HBUF_OFF_BIG : XPACK_OFF;
    char*   hbuf  = ws + hbuf_off;
    unsigned* cnts = (unsigned*)(ws + hbuf_off + HBUF_BYTES);

    (void)hipFuncSetAttribute((const void*)persist_kernel,
                              hipFuncAttributeMaxDynamicSharedMemorySize, 104448);

    hipMemsetAsync(cnts, 0, 4096, stream);
    pack_kernel<<<816, 256, 0, stream>>>(Wx, Uh, Uh2, packW);
    if (use_xp)
        xpack_kernel<<<6728, 256, 0, stream>>>(x, xpack);

    void* args[] = { (void*)&x, (void*)&xpack, (void*)&packW, (void*)&b,
                     (void*)&hbuf, (void*)&cnts };
    hipLaunchCooperativeKernel((void*)persist_kernel, dim3(256), dim3(512),
                               args, 104448, stream);

    out_kernel<<<256, 64, 0, stream>>>(hbuf, Wout, bout, out);
}

// Round 7
// 1969.135 us; speedup vs baseline: 1.4205x; 1.4205x over previous
//
#include <hip/hip_runtime.h>

typedef __bf16 bf16x8 __attribute__((ext_vector_type(8)));
typedef float  f32x4  __attribute__((ext_vector_type(4)));

union U4 { uint4 u; bf16x8 v; };

__device__ __forceinline__ bf16x8 ld_frag(const void* p) {
    U4 t; t.u = *(const uint4*)p; return t.v;
}
__device__ __forceinline__ bf16x8 zfrag() {
    bf16x8 z;
#pragma unroll
    for (int jj = 0; jj < 8; jj++) z[jj] = (__bf16)0.f;
    return z;
}
__device__ __forceinline__ unsigned bf16_bits(float f) {
    __bf16 h = (__bf16)f; unsigned short s;
    __builtin_memcpy(&s, &h, 2); return (unsigned)s;
}
__device__ __forceinline__ float bf16_lo(unsigned v) {
    unsigned u = (v & 0xffffu) << 16; float f;
    __builtin_memcpy(&f, &u, 4); return f;
}
__device__ __forceinline__ float bf16_hi(unsigned v) {
    unsigned u = v & 0xffff0000u; float f;
    __builtin_memcpy(&f, &u, 4); return f;
}

__device__ __forceinline__ void gl_lds16(const uint4* g, void* l) {
    __builtin_amdgcn_global_load_lds(
        (const __attribute__((address_space(1))) unsigned int*)g,
        (__attribute__((address_space(3))) unsigned int*)l, 16, 0, 0);
}

__device__ __forceinline__ float sigf(float x) {
    return __builtin_amdgcn_rcpf(1.f + __expf(-x));
}
__device__ __forceinline__ float tanhf_fast(float x) {
    return 1.f - 2.f * __builtin_amdgcn_rcpf(1.f + __expf(2.f * x));
}

#define MFMA(A,B,C) C = __builtin_amdgcn_mfma_f32_16x16x32_bf16(A, B, C, 0, 0, 0)

// ---------------------------------------------------------------------------
// pack: [Wx(16,pad 32); Uh(256); Uh2(256)] -> B-fragments.
// For kt>=1 (h stages) the 32 k-rows within a stage are PERMUTED:
//   fragment position p (0..31) holds k-row kt*32 + pi(p), pi(p)=(p&1)*16+(p>>1).
// The h-slice storage uses the same permutation, making the epilogue's
// 2-col write a single dword. MFMA is order-invariant when A and B agree.
// kt=0 (x stage) keeps identity order (matches xpack).
// ---------------------------------------------------------------------------
__global__ void pack_kernel(const float* __restrict__ Wx, const float* __restrict__ Uh,
                            const float* __restrict__ Uh2, uint4* __restrict__ packW) {
    int tid = blockIdx.x * 256 + threadIdx.x;   // 4*17*48*64 = 208896
    int lane = tid & 63;
    int nt   = (tid >> 6) % 48;
    int kt   = ((tid >> 6) / 48) % 17;
    int a    = (tid >> 6) / (48 * 17);
    int col  = nt * 16 + (lane & 15);
    U4 u;
#pragma unroll
    for (int jj = 0; jj < 8; jj++) {
        int p  = (lane >> 4) * 8 + jj;
        int kk = (kt == 0) ? p : (((p & 1) << 4) | (p >> 1));
        int k  = kt * 32 + kk;
        float v;
        if (k < 16)       v = Wx[(a * 16 + k) * 768 + col];
        else if (k < 32)  v = 0.f;
        else if (k < 288) v = Uh[(a * 256 + (k - 32)) * 768 + col];
        else              v = Uh2[(a * 256 + (k - 288)) * 768 + col];
        u.v[jj] = (__bf16)v;
    }
    packW[tid] = u.u;
}

// xpack[a][i29][j29][m256][q2] = 8 bf16 of patch element k=q*8+jj (identity order)
__global__ void xpack_kernel(const float* __restrict__ x, uint4* __restrict__ xp) {
    int tid = blockIdx.x * 256 + threadIdx.x;   // 1,722,368
    int q = tid & 1;
    int m = (tid >> 1) & 255;
    int rem = tid >> 9;
    int j = rem % 29;
    int t2 = rem / 29;
    int i = t2 % 29;
    int a = t2 / 29;
    int Ny = 29 - (a & 1), Nx = 29 - ((a >> 1) & 1);
    U4 u;
    if (i < Ny && j < Nx) {
        int y0 = (a & 1) ? (27 - i) : i;
        int x0 = (a & 2) ? (27 - j) : j;
        const float* px = x + m * 1024 + y0 * 32 + x0;
#pragma unroll
        for (int jj = 0; jj < 8; jj++) {
            int k = q * 8 + jj;
            u.v[jj] = (__bf16)px[(k >> 2) * 32 + (k & 3)];
        }
    } else {
#pragma unroll
        for (int jj = 0; jj < 8; jj++) u.v[jj] = (__bf16)0.f;
    }
    xp[tid] = u.u;
}

// ---------------------------------------------------------------------------
// Persistent kernel. 256 blocks x 512 thr (cooperative). Block = (G, r):
//   G = bx&7 : group (a = G>>1 direction, hb = G&1 batch-half, M=128)
//   r = bx>>3: g = r&7 (32 hidden cols), qi0 = r>>3
// Per-group 32-block barrier per diagonal with __threadfence() release/acquire
// (wbL2 + invL1/L2) -> h loads/stores in the loop are PLAIN cached ops; the 8x
// g-redundant slice reads hit local L2, coherence established only at barriers.
// B for (a,g) in 102 KB LDS (loaded once). Wave-pair wp handles one cell;
// wave wv covers M64 x N96 (acc[4][6]).
// hbuf per group: [p2][j29][kt8][m128][c32-permuted] bf16 (slice 65536 B).
// ---------------------------------------------------------------------------
__global__ __launch_bounds__(512, 2) void persist_kernel(
    const float* __restrict__ x, const uint4* __restrict__ xpack,
    const uint4* __restrict__ packW, const float* __restrict__ bias,
    char* __restrict__ hbuf, unsigned* __restrict__ cnts)
{
    extern __shared__ __align__(16) unsigned char smem[];   // 104448 B

    int bx = blockIdx.x;
    int G  = bx & 7;
    int r  = bx >> 3;
    int a  = G >> 1, hb = G & 1;
    int g  = r & 7, qi0 = r >> 3;
    int Ny = 29 - (a & 1), Nx = 29 - ((a >> 1) & 1);
    int Dg = Ny + Nx - 1;
    char* hbg = hbuf + (size_t)G * 3801088;
    unsigned* cnt = cnts + G * 32;   // 128 B spacing

    int tid  = threadIdx.x;
    int w8   = tid >> 6;
    int wp   = tid >> 7;
    int wv   = (tid >> 6) & 1;
    int lane = tid & 63;
    int q    = lane >> 4;
    int l16  = lane & 15;

    // ---- one-time B preload: 102 chunks x 1 KB ----
    for (int c = w8; c < 102; c += 8) {
        int s  = c / 6;
        int cc = c - s * 6;
        int kt = (s == 16) ? 0 : (s + 1);
        int nt = (cc >> 1) * 16 + 2 * g + (cc & 1);
        gl_lds16(packW + (size_t)(a * 17 + kt) * 3072 + nt * 64 + lane,
                 smem + (size_t)c * 1024);
    }
    __syncthreads();

    int rowoff = wv * 4096 + l16 * 64 + q * 16;
    const float* ba = bias + a * 768;
    int c0 = g * 32 + l16;           // half-0 col, half-1 col = c0+16
    float bR0 = ba[c0],       bZ0 = ba[256 + c0],       bN0 = ba[512 + c0];
    float bR1 = ba[c0 + 16],  bZ1 = ba[256 + c0 + 16],  bN1 = ba[512 + c0 + 16];

    for (int d = 0; d < Dg; ++d) {
        int lo = d - (Ny - 1); if (lo < 0) lo = 0;
        int hi = (d < Nx - 1) ? d : Nx - 1;
        int nquad = (hi - lo + 4) >> 2;
        int pprev = (d - 1) & 1;
        int pcur  = d & 1;

        for (int qi = qi0; qi < nquad; qi += 4) {
            int j = lo + qi * 4 + wp;
            if (j > hi) continue;                 // wave-pair-uniform
            int i = d - j;
            bool hasA = (i > 0);
            bool hasL = (j > 0);
            const char* sA = hbg + (size_t)(pprev * 29 + j) * 65536;
            const char* sL = hbg + (size_t)(pprev * 29 + (j - 1)) * 65536;

            f32x4 acc[4][6];
#pragma unroll
            for (int mt = 0; mt < 4; mt++)
#pragma unroll
                for (int cf = 0; cf < 6; cf++)
#pragma unroll
                    for (int e = 0; e < 4; e++) acc[mt][cf][e] = 0.f;

            bf16x8 af[4][4];
            bf16x8 afx[4];
            auto issueA = [&](int s, bf16x8* dst) {
                if (s >= 16) return;
                bool act = (s < 8) ? hasA : hasL;
                if (!act) return;
                const char* sb = ((s < 8) ? sA : sL) + (size_t)(s & 7) * 8192 + rowoff;
#pragma unroll
                for (int mt = 0; mt < 4; mt++) dst[mt] = ld_frag(sb + mt * 1024);
            };
            auto loadAfx = [&]() {
                if (xpack) {
                    const uint4* xpc = xpack + (size_t)((a * 29 + i) * 29 + j) * 512
                                      + (size_t)(hb * 128) * 2 + q;
#pragma unroll
                    for (int mt = 0; mt < 4; mt++) {
                        if (q < 2) afx[mt] = ld_frag(xpc + (wv * 64 + mt * 16 + l16) * 2);
                        else       afx[mt] = zfrag();
                    }
                } else {
                    int y0 = (a & 1) ? (27 - i) : i;
                    int x0 = (a & 2) ? (27 - j) : j;
#pragma unroll
                    for (int mt = 0; mt < 4; mt++) {
                        if (q < 2) {
                            int m = hb * 128 + wv * 64 + mt * 16 + l16;
                            const float* xp = x + m * 1024 + (y0 + 2 * q) * 32 + x0;
#pragma unroll
                            for (int jj = 0; jj < 8; jj++)
                                afx[mt][jj] = (__bf16)xp[(jj >> 2) * 32 + (jj & 3)];
                        } else afx[mt] = zfrag();
                    }
                }
            };
            auto compute = [&](const bf16x8* afc, int s) {
                const unsigned char* bb = smem + (size_t)s * 6144 + lane * 16;
#pragma unroll
                for (int cf = 0; cf < 6; cf++) {
                    bf16x8 bf = ld_frag(bb + cf * 1024);
#pragma unroll
                    for (int mt = 0; mt < 4; mt++) MFMA(afc[mt], bf, acc[mt][cf]);
                }
            };

            issueA(0, af[0]); issueA(1, af[1]); issueA(2, af[2]); issueA(3, af[3]);
#pragma unroll
            for (int s = 0; s < 16; ++s) {
                bool act = (s < 8) ? hasA : hasL;
                if (act) compute(af[s & 3], s);
                if (s == 13) loadAfx();           // 3 stages early: hide L3 miss
                issueA(s + 4, af[s & 3]);
            }

            // x contributions to r,z
            {
                const unsigned char* bb = smem + (size_t)16 * 6144 + lane * 16;
#pragma unroll
                for (int cf = 0; cf < 4; cf++) {
                    bf16x8 bf = ld_frag(bb + cf * 1024);
#pragma unroll
                    for (int mt = 0; mt < 4; mt++) MFMA(afx[mt], bf, acc[mt][cf]);
                }
            }
            // n-gate x-part for both halves, fused epilogue with dword h I/O
            char* sO = hbg + (size_t)(pcur * 29 + j) * 65536;
            bf16x8 bn0 = ld_frag(smem + (size_t)16 * 6144 + 4 * 1024 + lane * 16);
            bf16x8 bn1 = ld_frag(smem + (size_t)16 * 6144 + 5 * 1024 + lane * 16);
            f32x4 tn0[4], tn1[4];
#pragma unroll
            for (int mt = 0; mt < 4; mt++) {
                f32x4 z4 = {0.f, 0.f, 0.f, 0.f};
                tn0[mt] = __builtin_amdgcn_mfma_f32_16x16x32_bf16(afx[mt], bn0, z4, 0, 0, 0);
                tn1[mt] = __builtin_amdgcn_mfma_f32_16x16x32_bf16(afx[mt], bn1, z4, 0, 0, 0);
            }
#pragma unroll
            for (int mt = 0; mt < 4; mt++) {
#pragma unroll
                for (int e = 0; e < 4; e++) {
                    int m = wv * 64 + mt * 16 + q * 4 + e;
                    size_t off = (size_t)g * 8192 + (size_t)m * 64 + (size_t)l16 * 4;
                    float rv0 = sigf(acc[mt][0][e] + bR0);
                    float zv0 = sigf(acc[mt][2][e] + bZ0);
                    float nv0 = tanhf_fast(tn0[mt][e] + bN0 + rv0 * acc[mt][4][e]);
                    float rv1 = sigf(acc[mt][1][e] + bR1);
                    float zv1 = sigf(acc[mt][3][e] + bZ1);
                    float nv1 = tanhf_fast(tn1[mt][e] + bN1 + rv1 * acc[mt][5][e]);
                    float hs0 = 0.f, hs1 = 0.f;
                    if (hasA) {
                        unsigned v = *(const unsigned*)(sA + off);
                        hs0 += bf16_lo(v); hs1 += bf16_hi(v);
                    }
                    if (hasL) {
                        unsigned v = *(const unsigned*)(sL + off);
                        hs0 += bf16_lo(v); hs1 += bf16_hi(v);
                    }
                    float h0 = (1.f - zv0) * nv0 + 0.5f * zv0 * hs0;
                    float h1 = (1.f - zv1) * nv1 + 0.5f * zv1 * hs1;
                    *(unsigned*)(sO + off) = bf16_bits(h0) | (bf16_bits(h1) << 16);
                }
            }
        }

        // ---- per-group barrier with release/acquire cache maintenance ----
        __syncthreads();                       // drains this block's stores to L2
        if (tid == 0) {
            __threadfence();                   // release: write back dirty L2
            atomicAdd(cnt, 1u);
            unsigned need = 32u * (unsigned)(d + 1);
            while (__hip_atomic_load(cnt, __ATOMIC_RELAXED, __HIP_MEMORY_SCOPE_AGENT) < need)
                __builtin_amdgcn_s_sleep(2);
            __threadfence();                   // acquire: invalidate L1/L2
        }
        __syncthreads();
    }
}

// ---------------------------------------------------------------------------
// Output: logits = hcat @ W_out + b_out, then log_softmax. One wave per batch.
// h col c: kt-block c>>5, permuted position pos = ((c&15)<<1)|((c>>4)&1).
// ---------------------------------------------------------------------------
__global__ __launch_bounds__(64) void out_kernel(const char* __restrict__ hbuf,
    const float* __restrict__ Wout, const float* __restrict__ bout,
    float* __restrict__ out)
{
    int b = blockIdx.x;
    int tt = threadIdx.x;
    float accv[10];
#pragma unroll
    for (int o = 0; o < 10; o++) accv[o] = 0.f;
    for (int it = 0; it < 16; ++it) {
        int k = it * 64 + tt;
        int a = k >> 8, c = k & 255;
        int Ny = 29 - (a & 1), Nx = 29 - ((a >> 1) & 1);
        int pf = (Ny + Nx - 2) & 1;
        int jf = Nx - 1;
        int G  = a * 2 + (b >> 7);
        int c31 = c & 31;
        int pos = ((c31 & 15) << 1) | (c31 >> 4);
        const __bf16* hp = (const __bf16*)(hbuf + (size_t)G * 3801088
                           + (size_t)(pf * 29 + jf) * 65536
                           + (size_t)(c >> 5) * 8192 + (size_t)(b & 127) * 64
                           + (size_t)pos * 2);
        float h = (float)(*hp);
        const float* wr = Wout + k * 10;
#pragma unroll
        for (int o = 0; o < 10; o++) accv[o] += h * wr[o];
    }
#pragma unroll
    for (int off = 32; off > 0; off >>= 1)
#pragma unroll
        for (int o = 0; o < 10; o++) accv[o] += __shfl_down(accv[o], off, 64);
    if (tt == 0) {
        float l[10];
#pragma unroll
        for (int o = 0; o < 10; o++) l[o] = accv[o] + bout[o];
        float mx = l[0];
#pragma unroll
        for (int o = 1; o < 10; o++) mx = fmaxf(mx, l[o]);
        float se = 0.f;
#pragma unroll
        for (int o = 0; o < 10; o++) se += __expf(l[o] - mx);
        float lse = mx + __logf(se);
#pragma unroll
        for (int o = 0; o < 10; o++) out[b * 10 + o] = l[o] - lse;
    }
}

extern "C" void kernel_launch(void* const* d_in, const int* in_sizes, int n_in,
                              void* d_out, int out_size, void* d_ws, size_t ws_size,
                              hipStream_t stream) {
    const float* x    = (const float*)d_in[0];
    const float* Wx   = (const float*)d_in[1];
    const float* Uh   = (const float*)d_in[2];
    const float* Uh2  = (const float*)d_in[3];
    const float* b    = (const float*)d_in[4];
    const float* Wout = (const float*)d_in[5];
    const float* bout = (const float*)d_in[6];
    float* out = (float*)d_out;

    char* ws = (char*)d_ws;
    const size_t XPACK_OFF    = 3407872;
    const size_t HBUF_OFF_BIG = 31457280;
    const size_t HBUF_BYTES   = 30408704;
    bool use_xp = (ws_size >= HBUF_OFF_BIG + HBUF_BYTES + 4096);

    uint4*  packW = (uint4*)ws;
    uint4*  xpack = use_xp ? (uint4*)(ws + XPACK_OFF) : nullptr;
    size_t  hbuf_off = use_xp ? HBUF_OFF_BIG : XPACK_OFF;
    char*   hbuf  = ws + hbuf_off;
    unsigned* cnts = (unsigned*)(ws + hbuf_off + HBUF_BYTES);

    (void)hipFuncSetAttribute((const void*)persist_kernel,
                              hipFuncAttributeMaxDynamicSharedMemorySize, 104448);

    hipMemsetAsync(cnts, 0, 4096, stream);
    pack_kernel<<<816, 256, 0, stream>>>(Wx, Uh, Uh2, packW);
    if (use_xp)
        xpack_kernel<<<6728, 256, 0, stream>>>(x, xpack);

    void* args[] = { (void*)&x, (void*)&xpack, (void*)&packW, (void*)&b,
                     (void*)&hbuf, (void*)&cnts };
    hipLaunchCooperativeKernel((void*)persist_kernel, dim3(256), dim3(512),
                               args, 104448, stream);

    out_kernel<<<256, 64, 0, stream>>>(hbuf, Wout, bout, out);
}